// Round 1
// baseline (5094.097 us; speedup 1.0000x reference)
//
#include <hip/hip_runtime.h>
#include <math.h>

#define DD   512
#define NTOT 65536
#define RR   64
#define NB   2
#define EPSV 1e-6f

// ---------------------------------------------------------------------------
// colnorm: dst[:,r] = src[:,r] / max(||src[:,r]||_2, 1e-12), per (batch, r).
// grid = NB*RR blocks of 64 threads (one wave per column, D=512 -> 8/lane).
// ---------------------------------------------------------------------------
__global__ __launch_bounds__(64) void colnorm_kernel(const float* __restrict__ src,
                                                     float* __restrict__ dst) {
    int col = blockIdx.x;                 // s*64 + r
    int s = col >> 6, r = col & 63;
    const float* p = src + (size_t)s * DD * RR + r;
    float* q = dst + (size_t)s * DD * RR + r;
    int lane = threadIdx.x;
    float v[8];
    float ss = 0.f;
#pragma unroll
    for (int k = 0; k < 8; ++k) {
        v[k] = p[(size_t)(lane + 64 * k) * RR];
        ss += v[k] * v[k];
    }
#pragma unroll
    for (int m = 1; m < 64; m <<= 1) ss += __shfl_xor(ss, m);
    float inv = 1.f / fmaxf(sqrtf(ss), 1e-12f);
#pragma unroll
    for (int k = 0; k < 8; ++k)
        q[(size_t)(lane + 64 * k) * RR] = v[k] * inv;
}

// ---------------------------------------------------------------------------
// ata: out[k][j] += sum_n A[n][k]*A[n][j]  (A is (K,64) row-major, per batch).
// Used for BtB (K=512) and CtC (K=65536). out must be pre-zeroed; atomicAdd.
// grid = (K/rpb, NB), 256 threads, 4x4 register tile.
// ---------------------------------------------------------------------------
__global__ __launch_bounds__(256) void ata_kernel(const float* __restrict__ A,
                                                  float* __restrict__ outp,
                                                  int rpb, long bstride) {
    int s = blockIdx.y;
    long r0 = (long)blockIdx.x * rpb;
    const float* Ap = A + (size_t)s * bstride;
    float* op = outp + (size_t)s * RR * RR;
    __shared__ __align__(16) float As[8][64];
    int tid = threadIdx.x, tx = tid & 15, ty = tid >> 4;
    float acc[4][4] = {};
    for (long n = r0; n < r0 + rpb; n += 8) {
#pragma unroll
        for (int k = 0; k < 2; ++k) {
            int idx = tid + k * 256;
            As[idx >> 6][idx & 63] = Ap[(size_t)(n + (idx >> 6)) * RR + (idx & 63)];
        }
        __syncthreads();
#pragma unroll
        for (int nn = 0; nn < 8; ++nn) {
            float4 av = *(const float4*)&As[nn][4 * ty];
            float4 bv = *(const float4*)&As[nn][4 * tx];
            float a0[4] = {av.x, av.y, av.z, av.w};
            float b0_[4] = {bv.x, bv.y, bv.z, bv.w};
#pragma unroll
            for (int i = 0; i < 4; ++i)
#pragma unroll
                for (int j = 0; j < 4; ++j)
                    acc[i][j] += a0[i] * b0_[j];
        }
        __syncthreads();
    }
#pragma unroll
    for (int i = 0; i < 4; ++i)
#pragma unroll
        for (int j = 0; j < 4; ++j)
            atomicAdd(&op[(4 * ty + i) * RR + 4 * tx + j], acc[i][j]);
}

// ---------------------------------------------------------------------------
// xtb: T[n,r] = sum_d X[d,n]*b[d,r] over a 64-row n tile (K=D=512).
// MODE 0: c[n,r] = softmax_r(T)                       (init coef, raw x)
// MODE 1: c[n,r] = cin*T / (sum_k cin[n,k]*BtB[k,r] + EPS)   (MU c-update)
//   cin clamped to EPS on load iff clamp_c (prev step's c2); result stored
//   UNclamped (reference clamps after CtC/numB consume it).
// grid = (NTOT/64, NB), 256 threads, 4x4 register tile.
// ---------------------------------------------------------------------------
template <int MODE>
__global__ __launch_bounds__(256) void xtb_kernel(const float* __restrict__ x,
                                                  const float* __restrict__ bmat,
                                                  const float* __restrict__ btbG,
                                                  float* __restrict__ c,
                                                  int clamp_x, int clamp_c) {
    int s = blockIdx.y;
    int n0 = blockIdx.x * 64;
    const float* xp = x + (size_t)s * DD * NTOT + n0;
    const float* bp = bmat + (size_t)s * DD * RR;
    float* cp = c + ((size_t)s * NTOT + n0) * RR;
    __shared__ __align__(16) float Xs[8][64];
    __shared__ __align__(16) float Bs[8][64];
    __shared__ __align__(16) float Cs[64][68];   // pad 68: <=2-way bank conflicts
    __shared__ __align__(16) float Bt[64][68];
    int tid = threadIdx.x, tx = tid & 15, ty = tid >> 4;

    if (MODE == 1) {
        const float* tp = btbG + (size_t)s * RR * RR;
#pragma unroll
        for (int k = 0; k < 16; ++k) {
            int idx = tid + k * 256;
            int kk = idx >> 6, jj = idx & 63;
            Bt[kk][jj] = tp[idx];
            float v = cp[(size_t)kk * RR + jj];
            if (clamp_c) v = fmaxf(v, EPSV);
            Cs[kk][jj] = v;
        }
    }

    float acc[4][4] = {};
    for (int d = 0; d < DD; d += 8) {
#pragma unroll
        for (int k = 0; k < 2; ++k) {
            int idx = tid + k * 256;
            int dd = idx >> 6, col = idx & 63;
            float xv = xp[(size_t)(d + dd) * NTOT + col];
            if (clamp_x) xv = fmaxf(xv, EPSV);
            Xs[dd][col] = xv;
            Bs[dd][col] = bp[(size_t)(d + dd) * RR + col];
        }
        __syncthreads();
#pragma unroll
        for (int dd = 0; dd < 8; ++dd) {
            float4 xa = *(const float4*)&Xs[dd][4 * ty];
            float4 ba = *(const float4*)&Bs[dd][4 * tx];
            float xr[4] = {xa.x, xa.y, xa.z, xa.w};
            float br[4] = {ba.x, ba.y, ba.z, ba.w};
#pragma unroll
            for (int i = 0; i < 4; ++i)
#pragma unroll
                for (int j = 0; j < 4; ++j)
                    acc[i][j] += xr[i] * br[j];
        }
        __syncthreads();
    }

    if (MODE == 0) {
        // row softmax across the 16-lane tx group (4 values per thread)
#pragma unroll
        for (int i = 0; i < 4; ++i) {
            float m = fmaxf(fmaxf(acc[i][0], acc[i][1]), fmaxf(acc[i][2], acc[i][3]));
            m = fmaxf(m, __shfl_xor(m, 1));
            m = fmaxf(m, __shfl_xor(m, 2));
            m = fmaxf(m, __shfl_xor(m, 4));
            m = fmaxf(m, __shfl_xor(m, 8));
            float e0 = __expf(acc[i][0] - m);
            float e1 = __expf(acc[i][1] - m);
            float e2 = __expf(acc[i][2] - m);
            float e3 = __expf(acc[i][3] - m);
            float ssum = e0 + e1 + e2 + e3;
            ssum += __shfl_xor(ssum, 1);
            ssum += __shfl_xor(ssum, 2);
            ssum += __shfl_xor(ssum, 4);
            ssum += __shfl_xor(ssum, 8);
            float invs = 1.f / ssum;
            float4 o;
            o.x = e0 * invs; o.y = e1 * invs; o.z = e2 * invs; o.w = e3 * invs;
            *(float4*)&cp[(size_t)(4 * ty + i) * RR + 4 * tx] = o;
        }
    } else {
#pragma unroll
        for (int i = 0; i < 4; ++i) {
            int n = 4 * ty + i;
            float den[4] = {};
#pragma unroll
            for (int k = 0; k < 64; ++k) {
                float cv = Cs[n][k];
                float4 bt = *(const float4*)&Bt[k][4 * tx];
                den[0] += cv * bt.x;
                den[1] += cv * bt.y;
                den[2] += cv * bt.z;
                den[3] += cv * bt.w;
            }
            float4 o;
            o.x = Cs[n][4 * tx + 0] * acc[i][0] / (den[0] + EPSV);
            o.y = Cs[n][4 * tx + 1] * acc[i][1] / (den[1] + EPSV);
            o.z = Cs[n][4 * tx + 2] * acc[i][2] / (den[2] + EPSV);
            o.w = Cs[n][4 * tx + 3] * acc[i][3] / (den[3] + EPSV);
            *(float4*)&cp[(size_t)n * RR + 4 * tx] = o;
        }
    }
}

// ---------------------------------------------------------------------------
// xtc: numB[d,r] += sum_n max(x[d,n],EPS) * c[n,r]  (K=N reduction, atomics).
// grid = (NTOT/npb, DD/64, NB), 256 threads, 4x4 tile over (d,r).
// ---------------------------------------------------------------------------
__global__ __launch_bounds__(256) void xtc_kernel(const float* __restrict__ x,
                                                  const float* __restrict__ c,
                                                  float* __restrict__ numB,
                                                  int npb) {
    int s = blockIdx.z;
    int d0 = blockIdx.y * 64;
    long n0 = (long)blockIdx.x * npb;
    const float* xp = x + ((size_t)s * DD + d0) * NTOT;
    const float* cp = c + (size_t)s * NTOT * RR;
    __shared__ __align__(16) float Xs[64][20];   // pad 20: 16B-aligned float4 rows
    __shared__ __align__(16) float Cs[16][64];
    int tid = threadIdx.x, tx = tid & 15, ty = tid >> 4;
    float acc[4][4] = {};
    for (long n = n0; n < n0 + npb; n += 16) {
#pragma unroll
        for (int k = 0; k < 4; ++k) {
            int idx = tid + k * 256;
            int dd = idx >> 4, nn = idx & 15;
            Xs[dd][nn] = fmaxf(xp[(size_t)dd * NTOT + n + nn], EPSV);
        }
#pragma unroll
        for (int k = 0; k < 4; ++k) {
            int idx = tid + k * 256;
            int nn = idx >> 6, col = idx & 63;
            Cs[nn][col] = cp[(size_t)(n + nn) * RR + col];
        }
        __syncthreads();
#pragma unroll
        for (int q = 0; q < 4; ++q) {
            float4 xa[4], ca[4];
#pragma unroll
            for (int i = 0; i < 4; ++i) xa[i] = *(const float4*)&Xs[4 * ty + i][4 * q];
#pragma unroll
            for (int t = 0; t < 4; ++t) ca[t] = *(const float4*)&Cs[4 * q + t][4 * tx];
#pragma unroll
            for (int i = 0; i < 4; ++i) {
                float xv[4] = {xa[i].x, xa[i].y, xa[i].z, xa[i].w};
#pragma unroll
                for (int t = 0; t < 4; ++t) {
                    float cj[4] = {ca[t].x, ca[t].y, ca[t].z, ca[t].w};
#pragma unroll
                    for (int j = 0; j < 4; ++j)
                        acc[i][j] += xv[t] * cj[j];
                }
            }
        }
        __syncthreads();
    }
    float* op = numB + ((size_t)s * DD + d0) * RR;
#pragma unroll
    for (int i = 0; i < 4; ++i)
#pragma unroll
        for (int j = 0; j < 4; ++j)
            atomicAdd(&op[(4 * ty + i) * RR + 4 * tx + j], acc[i][j]);
}

// ---------------------------------------------------------------------------
// updb: bout = max( b*numB / (b@CtC + EPS), EPS )   (unnormalized; colnorm next)
// grid = (DD/64, NB)
// ---------------------------------------------------------------------------
__global__ __launch_bounds__(256) void updb_kernel(const float* __restrict__ bin,
                                                   const float* __restrict__ numB,
                                                   const float* __restrict__ ctcG,
                                                   float* __restrict__ bout) {
    int s = blockIdx.y;
    int d0 = blockIdx.x * 64;
    const float* bp = bin + ((size_t)s * DD + d0) * RR;
    const float* np_ = numB + ((size_t)s * DD + d0) * RR;
    float* op = bout + ((size_t)s * DD + d0) * RR;
    const float* cc = ctcG + (size_t)s * RR * RR;
    __shared__ __align__(16) float Bsh[64][68];
    __shared__ __align__(16) float Ct[64][68];
    int tid = threadIdx.x, tx = tid & 15, ty = tid >> 4;
#pragma unroll
    for (int k = 0; k < 16; ++k) {
        int idx = tid + k * 256;
        int r_ = idx >> 6, col = idx & 63;
        Bsh[r_][col] = bp[idx];
        Ct[r_][col] = cc[idx];
    }
    __syncthreads();
#pragma unroll
    for (int i = 0; i < 4; ++i) {
        int d = 4 * ty + i;
        float den[4] = {};
#pragma unroll
        for (int k = 0; k < 64; ++k) {
            float bv = Bsh[d][k];
            float4 ct = *(const float4*)&Ct[k][4 * tx];
            den[0] += bv * ct.x;
            den[1] += bv * ct.y;
            den[2] += bv * ct.z;
            den[3] += bv * ct.w;
        }
        float4 b4 = *(const float4*)&Bsh[d][4 * tx];
        float4 n4 = *(const float4*)&np_[(size_t)d * RR + 4 * tx];
        float4 o;
        o.x = fmaxf(b4.x * n4.x / (den[0] + EPSV), EPSV);
        o.y = fmaxf(b4.y * n4.y / (den[1] + EPSV), EPSV);
        o.z = fmaxf(b4.z * n4.z / (den[2] + EPSV), EPSV);
        o.w = fmaxf(b4.w * n4.w / (den[3] + EPSV), EPSV);
        *(float4*)&op[(size_t)d * RR + 4 * tx] = o;
    }
}

// ---------------------------------------------------------------------------
// xhat: out[d,n] = sum_r b[d,r]*c_new[n,r]   (K=64)
// grid = (NTOT/64, DD/64, NB); thread owns strided rows (ty+16i, tx+16j).
// ---------------------------------------------------------------------------
__global__ __launch_bounds__(256) void xhat_kernel(const float* __restrict__ bmat,
                                                   const float* __restrict__ c,
                                                   float* __restrict__ outp) {
    int s = blockIdx.z;
    int d0 = blockIdx.y * 64;
    int n0 = blockIdx.x * 64;
    const float* bp = bmat + ((size_t)s * DD + d0) * RR;
    const float* cp = c + ((size_t)s * NTOT + n0) * RR;
    float* op = outp + ((size_t)s * DD + d0) * NTOT + n0;
    __shared__ __align__(16) float Bsh[64][68];
    __shared__ __align__(16) float Cs[64][68];
    int tid = threadIdx.x, tx = tid & 15, ty = tid >> 4;
#pragma unroll
    for (int k = 0; k < 16; ++k) {
        int idx = tid + k * 256;
        int row = idx >> 6, col = idx & 63;
        Bsh[row][col] = bp[idx];
        Cs[row][col] = cp[(size_t)row * RR + col];
    }
    __syncthreads();
    float acc[4][4] = {};
#pragma unroll
    for (int q = 0; q < 16; ++q) {
        float4 bv[4], cv[4];
#pragma unroll
        for (int i = 0; i < 4; ++i) bv[i] = *(const float4*)&Bsh[ty + 16 * i][4 * q];
#pragma unroll
        for (int j = 0; j < 4; ++j) cv[j] = *(const float4*)&Cs[tx + 16 * j][4 * q];
#pragma unroll
        for (int i = 0; i < 4; ++i)
#pragma unroll
            for (int j = 0; j < 4; ++j)
                acc[i][j] += bv[i].x * cv[j].x + bv[i].y * cv[j].y +
                             bv[i].z * cv[j].z + bv[i].w * cv[j].w;
    }
#pragma unroll
    for (int i = 0; i < 4; ++i)
#pragma unroll
        for (int j = 0; j < 4; ++j)
            op[(size_t)(ty + 16 * i) * NTOT + tx + 16 * j] = acc[i][j];
}

// ---------------------------------------------------------------------------
extern "C" void kernel_launch(void* const* d_in, const int* in_sizes, int n_in,
                              void* d_out, int out_size, void* d_ws, size_t ws_size,
                              hipStream_t stream) {
    const float* x = (const float*)d_in[0];      // (2,512,16,64,64) -> (2,512,65536)
    const float* bases = (const float*)d_in[1];  // (2,512,64)
    float* out = (float*)d_out;
    float* ws = (float*)d_ws;

    // ws layout (floats): c | b0 | b1 | BtB | CtC | numB   (~34.4 MB total)
    float* c = ws;
    float* b0 = c + (size_t)NB * NTOT * RR;
    float* b1 = b0 + (size_t)NB * DD * RR;
    float* btb = b1 + (size_t)NB * DD * RR;
    float* ctc = btb + (size_t)NB * RR * RR;
    float* nB = ctc + (size_t)NB * RR * RR;

    // b = l2norm(bases, dim=D); BtB = b^T b
    colnorm_kernel<<<NB * RR, 64, 0, stream>>>(bases, b0);
    hipMemsetAsync(btb, 0, (size_t)NB * RR * RR * sizeof(float), stream);
    ata_kernel<<<dim3(8, NB), 256, 0, stream>>>(b0, btb, 64, (long)DD * RR);

    // coef = softmax(x^T b)  (raw x, no clamp)
    xtb_kernel<0><<<dim3(NTOT / 64, NB), 256, 0, stream>>>(x, b0, btb, c, 0, 0);

    float* bcur = b0;
    float* bnxt = b1;
    for (int step = 0; step < 6; ++step) {
        // c = clamp?(c) * (xc^T b) / (clamp?(c) @ BtB + EPS)   [stored unclamped]
        xtb_kernel<1><<<dim3(NTOT / 64, NB), 256, 0, stream>>>(
            x, bcur, btb, c, 1, step > 0 ? 1 : 0);
        // CtC = c^T c ; numB = xc @ c   (on the unclamped fresh c)
        hipMemsetAsync(ctc, 0, (size_t)NB * RR * RR * sizeof(float), stream);
        hipMemsetAsync(nB, 0, (size_t)NB * DD * RR * sizeof(float), stream);
        ata_kernel<<<dim3(128, NB), 256, 0, stream>>>(c, ctc, 512, (long)NTOT * RR);
        xtc_kernel<<<dim3(64, 8, NB), 256, 0, stream>>>(x, c, nB, 1024);
        // b = l2norm( max(b*numB/(b@CtC+EPS), EPS) ) ; BtB = b^T b
        updb_kernel<<<dim3(8, NB), 256, 0, stream>>>(bcur, nB, ctc, bnxt);
        colnorm_kernel<<<NB * RR, 64, 0, stream>>>(bnxt, bnxt);
        float* t = bcur; bcur = bnxt; bnxt = t;
        hipMemsetAsync(btb, 0, (size_t)NB * RR * RR * sizeof(float), stream);
        ata_kernel<<<dim3(8, NB), 256, 0, stream>>>(bcur, btb, 64, (long)DD * RR);
    }

    // compute_coef: c_new = clamp(coef) * (xc^T b) / (clamp(coef)@BtB + EPS)
    xtb_kernel<1><<<dim3(NTOT / 64, NB), 256, 0, stream>>>(x, bcur, btb, c, 1, 1);

    // x_hat = b @ c_new^T
    xhat_kernel<<<dim3(NTOT / 64, DD / 64, NB), 256, 0, stream>>>(bcur, c, out);
}

// Round 2
// 2889.630 us; speedup vs baseline: 1.7629x; 1.7629x over previous
//
#include <hip/hip_runtime.h>
#include <math.h>

#define DD   512
#define NTOT 65536
#define RR   64
#define NB   2
#define EPSV 1e-6f

// ---------------------------------------------------------------------------
// colnorm: dst[:,r] = src[:,r] / max(||src[:,r]||_2, 1e-12), per (batch, r).
// ---------------------------------------------------------------------------
__global__ __launch_bounds__(64) void colnorm_kernel(const float* __restrict__ src,
                                                     float* __restrict__ dst) {
    int col = blockIdx.x;                 // s*64 + r
    int s = col >> 6, r = col & 63;
    const float* p = src + (size_t)s * DD * RR + r;
    float* q = dst + (size_t)s * DD * RR + r;
    int lane = threadIdx.x;
    float v[8];
    float ss = 0.f;
#pragma unroll
    for (int k = 0; k < 8; ++k) {
        v[k] = p[(size_t)(lane + 64 * k) * RR];
        ss += v[k] * v[k];
    }
#pragma unroll
    for (int m = 1; m < 64; m <<= 1) ss += __shfl_xor(ss, m);
    float inv = 1.f / fmaxf(sqrtf(ss), 1e-12f);
#pragma unroll
    for (int k = 0; k < 8; ++k)
        q[(size_t)(lane + 64 * k) * RR] = v[k] * inv;
}

// ---------------------------------------------------------------------------
// ata2: out[k][j] += sum_n A[n][k]*A[n][j]; 32-row chunks, prefetched.
// grid = (K/rpb, NB); out pre-zeroed; atomicAdd epilogue.
// ---------------------------------------------------------------------------
__global__ __launch_bounds__(256) void ata2_kernel(const float* __restrict__ A,
                                                   float* __restrict__ outp,
                                                   int rpb, long bstride) {
    int s = blockIdx.y;
    long r0 = (long)blockIdx.x * rpb;
    const float* Ap = A + (size_t)s * bstride;
    float* op = outp + (size_t)s * RR * RR;
    __shared__ __align__(16) float As[32][68];
    int tid = threadIdx.x, tx = tid & 15, ty = tid >> 4;
    float4 g[2];
#pragma unroll
    for (int w = 0; w < 2; ++w) {
        int f4 = w * 256 + tid, row = f4 >> 4, c4 = f4 & 15;
        g[w] = *(const float4*)&Ap[(size_t)(r0 + row) * RR + 4 * c4];
    }
    float acc[4][4] = {};
    int nst = rpb / 32;
    for (int st = 0; st < nst; ++st) {
        __syncthreads();
#pragma unroll
        for (int w = 0; w < 2; ++w) {
            int f4 = w * 256 + tid, row = f4 >> 4, c4 = f4 & 15;
            *(float4*)&As[row][4 * c4] = g[w];
        }
        if (st + 1 < nst) {
            long rb = r0 + (long)(st + 1) * 32;
#pragma unroll
            for (int w = 0; w < 2; ++w) {
                int f4 = w * 256 + tid, row = f4 >> 4, c4 = f4 & 15;
                g[w] = *(const float4*)&Ap[(size_t)(rb + row) * RR + 4 * c4];
            }
        }
        __syncthreads();
#pragma unroll
        for (int k = 0; k < 32; ++k) {
            float4 av = *(const float4*)&As[k][4 * ty];
            float4 bv = *(const float4*)&As[k][4 * tx];
            float ar[4] = {av.x, av.y, av.z, av.w};
            float br[4] = {bv.x, bv.y, bv.z, bv.w};
#pragma unroll
            for (int i = 0; i < 4; ++i)
#pragma unroll
                for (int j = 0; j < 4; ++j) acc[i][j] += ar[i] * br[j];
        }
    }
#pragma unroll
    for (int i = 0; i < 4; ++i)
#pragma unroll
        for (int j = 0; j < 4; ++j)
            atomicAdd(&op[(4 * ty + i) * RR + 4 * tx + j], acc[i][j]);
}

// ---------------------------------------------------------------------------
// cden: den[n][r] = sum_k clamp?(c[n][k]) * BtB[k][r] + EPS   (K=64)
// grid = (NTOT/64, NB), 256 threads, 4x4 tile, float4 LDS reads.
// ---------------------------------------------------------------------------
__global__ __launch_bounds__(256) void cden_kernel(const float* __restrict__ c,
                                                   const float* __restrict__ btb,
                                                   float* __restrict__ den,
                                                   int clamp_c) {
    int s = blockIdx.y;
    int n0 = blockIdx.x * 64;
    const float* cpt = c + ((size_t)s * NTOT + n0) * RR;
    const float* tp = btb + (size_t)s * RR * RR;
    float* dp = den + ((size_t)s * NTOT + n0) * RR;
    __shared__ __align__(16) float Cs[64][68];
    __shared__ __align__(16) float Bt[64][68];
    int tid = threadIdx.x, tx = tid & 15, ty = tid >> 4;
#pragma unroll
    for (int w = 0; w < 16; ++w) {
        int idx = w * 256 + tid, row = idx >> 6, col = idx & 63;
        float v = cpt[(size_t)row * RR + col];
        if (clamp_c) v = fmaxf(v, EPSV);
        Cs[row][col] = v;
        Bt[row][col] = tp[idx];
    }
    __syncthreads();
    float a[4][4] = {};
#pragma unroll
    for (int q = 0; q < 16; ++q) {
        float4 cq[4], bq[4];
#pragma unroll
        for (int i = 0; i < 4; ++i) cq[i] = *(const float4*)&Cs[4 * ty + i][4 * q];
#pragma unroll
        for (int e = 0; e < 4; ++e) bq[e] = *(const float4*)&Bt[4 * q + e][4 * tx];
#pragma unroll
        for (int i = 0; i < 4; ++i) {
            float cv[4] = {cq[i].x, cq[i].y, cq[i].z, cq[i].w};
#pragma unroll
            for (int e = 0; e < 4; ++e) {
                float bj[4] = {bq[e].x, bq[e].y, bq[e].z, bq[e].w};
#pragma unroll
                for (int j = 0; j < 4; ++j) a[i][j] += cv[e] * bj[j];
            }
        }
    }
#pragma unroll
    for (int i = 0; i < 4; ++i) {
        float4 o;
        o.x = a[i][0] + EPSV; o.y = a[i][1] + EPSV;
        o.z = a[i][2] + EPSV; o.w = a[i][3] + EPSV;
        *(float4*)&dp[(size_t)(4 * ty + i) * RR + 4 * tx] = o;
    }
}

// ---------------------------------------------------------------------------
// xtb2: T[n,r] = sum_d X[d,n]*b[d,r] over a 256-row n tile (K=D=512).
// MODE 0: c = softmax_r(T) (raw x). MODE 1: c = clamp?(cin)*T/den.
// 256 threads, 8x8 register tile, K-chunk 16, register-prefetched staging.
// grid = (NTOT/256, NB) = 512 blocks = 2/CU.
// ---------------------------------------------------------------------------
template <int MODE>
__global__ __launch_bounds__(256, 2) void xtb2_kernel(const float* __restrict__ x,
                                                      const float* __restrict__ bmat,
                                                      const float* __restrict__ den,
                                                      float* __restrict__ c,
                                                      int clamp_x, int clamp_c) {
    int s = blockIdx.y;
    int n0 = blockIdx.x * 256;
    const float* xp = x + (size_t)s * DD * NTOT + n0;
    const float* bp = bmat + (size_t)s * DD * RR;
    float* cp = c + ((size_t)s * NTOT + n0) * RR;
    const float* dp = (MODE == 1) ? den + ((size_t)s * NTOT + n0) * RR : nullptr;
    __shared__ __align__(16) float Xs[16][256];
    __shared__ __align__(16) float Bs[16][64];
    int tid = threadIdx.x, tx = tid & 7, ty = tid >> 3;
    float clampv = clamp_x ? EPSV : -3.0e38f;

    float4 gx[4];
    float4 gb;
#pragma unroll
    for (int w = 0; w < 4; ++w) {
        int idx = w * 256 + tid, row = idx >> 6, c4 = idx & 63;
        gx[w] = *(const float4*)&xp[(size_t)row * NTOT + 4 * c4];
    }
    {
        int row = tid >> 4, c4 = tid & 15;
        gb = *(const float4*)&bp[(size_t)row * RR + 4 * c4];
    }

    float acc[8][8] = {};
    for (int st = 0; st < 32; ++st) {
        __syncthreads();
#pragma unroll
        for (int w = 0; w < 4; ++w) {
            int idx = w * 256 + tid, row = idx >> 6, c4 = idx & 63;
            float4 v = gx[w];
            v.x = fmaxf(v.x, clampv); v.y = fmaxf(v.y, clampv);
            v.z = fmaxf(v.z, clampv); v.w = fmaxf(v.w, clampv);
            *(float4*)&Xs[row][4 * c4] = v;
        }
        {
            int row = tid >> 4, c4 = tid & 15;
            *(float4*)&Bs[row][4 * c4] = gb;
        }
        if (st + 1 < 32) {
            int d0 = (st + 1) * 16;
#pragma unroll
            for (int w = 0; w < 4; ++w) {
                int idx = w * 256 + tid, row = idx >> 6, c4 = idx & 63;
                gx[w] = *(const float4*)&xp[(size_t)(d0 + row) * NTOT + 4 * c4];
            }
            int row = tid >> 4, c4 = tid & 15;
            gb = *(const float4*)&bp[(size_t)(d0 + row) * RR + 4 * c4];
        }
        __syncthreads();
#pragma unroll
        for (int k = 0; k < 16; ++k) {
            float4 x0 = *(const float4*)&Xs[k][8 * ty];
            float4 x1 = *(const float4*)&Xs[k][8 * ty + 4];
            float4 b0 = *(const float4*)&Bs[k][8 * tx];
            float4 b1 = *(const float4*)&Bs[k][8 * tx + 4];
            float xr[8] = {x0.x, x0.y, x0.z, x0.w, x1.x, x1.y, x1.z, x1.w};
            float br[8] = {b0.x, b0.y, b0.z, b0.w, b1.x, b1.y, b1.z, b1.w};
#pragma unroll
            for (int i = 0; i < 8; ++i)
#pragma unroll
                for (int j = 0; j < 8; ++j) acc[i][j] += xr[i] * br[j];
        }
    }

    if (MODE == 0) {
#pragma unroll
        for (int i = 0; i < 8; ++i) {
            float m = acc[i][0];
#pragma unroll
            for (int j = 1; j < 8; ++j) m = fmaxf(m, acc[i][j]);
            m = fmaxf(m, __shfl_xor(m, 1));
            m = fmaxf(m, __shfl_xor(m, 2));
            m = fmaxf(m, __shfl_xor(m, 4));
            float e[8];
            float ssum = 0.f;
#pragma unroll
            for (int j = 0; j < 8; ++j) {
                e[j] = expf(acc[i][j] - m);
                ssum += e[j];
            }
            ssum += __shfl_xor(ssum, 1);
            ssum += __shfl_xor(ssum, 2);
            ssum += __shfl_xor(ssum, 4);
            float inv = 1.f / ssum;
            size_t off = (size_t)(8 * ty + i) * RR + 8 * tx;
            float4 o0, o1;
            o0.x = e[0] * inv; o0.y = e[1] * inv; o0.z = e[2] * inv; o0.w = e[3] * inv;
            o1.x = e[4] * inv; o1.y = e[5] * inv; o1.z = e[6] * inv; o1.w = e[7] * inv;
            *(float4*)&cp[off] = o0;
            *(float4*)&cp[off + 4] = o1;
        }
    } else {
#pragma unroll
        for (int i = 0; i < 8; ++i) {
            size_t off = (size_t)(8 * ty + i) * RR + 8 * tx;
            float4 c0 = *(const float4*)&cp[off];
            float4 c1 = *(const float4*)&cp[off + 4];
            float4 d0_ = *(const float4*)&dp[off];
            float4 d1_ = *(const float4*)&dp[off + 4];
            if (clamp_c) {
                c0.x = fmaxf(c0.x, EPSV); c0.y = fmaxf(c0.y, EPSV);
                c0.z = fmaxf(c0.z, EPSV); c0.w = fmaxf(c0.w, EPSV);
                c1.x = fmaxf(c1.x, EPSV); c1.y = fmaxf(c1.y, EPSV);
                c1.z = fmaxf(c1.z, EPSV); c1.w = fmaxf(c1.w, EPSV);
            }
            float4 o0, o1;
            o0.x = c0.x * acc[i][0] / d0_.x;
            o0.y = c0.y * acc[i][1] / d0_.y;
            o0.z = c0.z * acc[i][2] / d0_.z;
            o0.w = c0.w * acc[i][3] / d0_.w;
            o1.x = c1.x * acc[i][4] / d1_.x;
            o1.y = c1.y * acc[i][5] / d1_.y;
            o1.z = c1.z * acc[i][6] / d1_.z;
            o1.w = c1.w * acc[i][7] / d1_.w;
            *(float4*)&cp[off] = o0;
            *(float4*)&cp[off + 4] = o1;
        }
    }
}

// ---------------------------------------------------------------------------
// xtc2: numB[d,r] += sum_n max(x[d,n],EPS)*c[n,r]; transposed X tile in LDS,
// 32-n chunks, prefetched. grid = (32, DD/64, NB) = 512 blocks.
// ---------------------------------------------------------------------------
__global__ __launch_bounds__(256, 2) void xtc2_kernel(const float* __restrict__ x,
                                                      const float* __restrict__ c,
                                                      float* __restrict__ numB) {
    int s = blockIdx.z;
    int d0 = blockIdx.y * 64;
    long n0 = (long)blockIdx.x * 2048;
    const float* xp = x + ((size_t)s * DD + d0) * NTOT;
    const float* cp = c + (size_t)s * NTOT * RR;
    __shared__ __align__(16) float Xs[32][68];   // [n-in-chunk][d]
    __shared__ __align__(16) float Cs[32][68];   // [n-in-chunk][r]
    int tid = threadIdx.x, tx = tid & 15, ty = tid >> 4;

    float4 gx[2], gc[2];
#pragma unroll
    for (int w = 0; w < 2; ++w) {
        int f4 = w * 256 + tid;
        int dd = f4 >> 3, n4 = f4 & 7;
        gx[w] = *(const float4*)&xp[(size_t)dd * NTOT + n0 + 4 * n4];
        int row = f4 >> 4, c4 = f4 & 15;
        gc[w] = *(const float4*)&cp[(size_t)(n0 + row) * RR + 4 * c4];
    }

    float acc[4][4] = {};
    for (int st = 0; st < 64; ++st) {
        __syncthreads();
#pragma unroll
        for (int w = 0; w < 2; ++w) {
            int f4 = w * 256 + tid;
            int dd = f4 >> 3, n4 = f4 & 7;
            float4 v = gx[w];
            Xs[4 * n4 + 0][dd] = fmaxf(v.x, EPSV);
            Xs[4 * n4 + 1][dd] = fmaxf(v.y, EPSV);
            Xs[4 * n4 + 2][dd] = fmaxf(v.z, EPSV);
            Xs[4 * n4 + 3][dd] = fmaxf(v.w, EPSV);
            int row = f4 >> 4, c4 = f4 & 15;
            *(float4*)&Cs[row][4 * c4] = gc[w];
        }
        if (st + 1 < 64) {
            long n = n0 + (long)(st + 1) * 32;
#pragma unroll
            for (int w = 0; w < 2; ++w) {
                int f4 = w * 256 + tid;
                int dd = f4 >> 3, n4 = f4 & 7;
                gx[w] = *(const float4*)&xp[(size_t)dd * NTOT + n + 4 * n4];
                int row = f4 >> 4, c4 = f4 & 15;
                gc[w] = *(const float4*)&cp[(size_t)(n + row) * RR + 4 * c4];
            }
        }
        __syncthreads();
#pragma unroll
        for (int k = 0; k < 32; ++k) {
            float4 xv = *(const float4*)&Xs[k][4 * ty];
            float4 cv = *(const float4*)&Cs[k][4 * tx];
            float xr[4] = {xv.x, xv.y, xv.z, xv.w};
            float cr[4] = {cv.x, cv.y, cv.z, cv.w};
#pragma unroll
            for (int i = 0; i < 4; ++i)
#pragma unroll
                for (int j = 0; j < 4; ++j) acc[i][j] += xr[i] * cr[j];
        }
    }
    float* op = numB + ((size_t)s * DD + d0) * RR;
#pragma unroll
    for (int i = 0; i < 4; ++i)
#pragma unroll
        for (int j = 0; j < 4; ++j)
            atomicAdd(&op[(4 * ty + i) * RR + 4 * tx + j], acc[i][j]);
}

// ---------------------------------------------------------------------------
// updb: bout = max( b*numB / (b@CtC + EPS), EPS )
// ---------------------------------------------------------------------------
__global__ __launch_bounds__(256) void updb_kernel(const float* __restrict__ bin,
                                                   const float* __restrict__ numB,
                                                   const float* __restrict__ ctcG,
                                                   float* __restrict__ bout) {
    int s = blockIdx.y;
    int d0 = blockIdx.x * 64;
    const float* bp = bin + ((size_t)s * DD + d0) * RR;
    const float* np_ = numB + ((size_t)s * DD + d0) * RR;
    float* op = bout + ((size_t)s * DD + d0) * RR;
    const float* cc = ctcG + (size_t)s * RR * RR;
    __shared__ __align__(16) float Bsh[64][68];
    __shared__ __align__(16) float Ct[64][68];
    int tid = threadIdx.x, tx = tid & 15, ty = tid >> 4;
#pragma unroll
    for (int k = 0; k < 16; ++k) {
        int idx = tid + k * 256;
        int r_ = idx >> 6, col = idx & 63;
        Bsh[r_][col] = bp[idx];
        Ct[r_][col] = cc[idx];
    }
    __syncthreads();
#pragma unroll
    for (int i = 0; i < 4; ++i) {
        int d = 4 * ty + i;
        float den[4] = {};
#pragma unroll
        for (int k = 0; k < 64; ++k) {
            float bv = Bsh[d][k];
            float4 ct = *(const float4*)&Ct[k][4 * tx];
            den[0] += bv * ct.x;
            den[1] += bv * ct.y;
            den[2] += bv * ct.z;
            den[3] += bv * ct.w;
        }
        float4 b4 = *(const float4*)&Bsh[d][4 * tx];
        float4 n4 = *(const float4*)&np_[(size_t)d * RR + 4 * tx];
        float4 o;
        o.x = fmaxf(b4.x * n4.x / (den[0] + EPSV), EPSV);
        o.y = fmaxf(b4.y * n4.y / (den[1] + EPSV), EPSV);
        o.z = fmaxf(b4.z * n4.z / (den[2] + EPSV), EPSV);
        o.w = fmaxf(b4.w * n4.w / (den[3] + EPSV), EPSV);
        *(float4*)&op[(size_t)d * RR + 4 * tx] = o;
    }
}

// ---------------------------------------------------------------------------
// xhat: out[d,n] = sum_r b[d,r]*c_new[n,r]   (K=64)
// ---------------------------------------------------------------------------
__global__ __launch_bounds__(256) void xhat_kernel(const float* __restrict__ bmat,
                                                   const float* __restrict__ c,
                                                   float* __restrict__ outp) {
    int s = blockIdx.z;
    int d0 = blockIdx.y * 64;
    int n0 = blockIdx.x * 64;
    const float* bp = bmat + ((size_t)s * DD + d0) * RR;
    const float* cp = c + ((size_t)s * NTOT + n0) * RR;
    float* op = outp + ((size_t)s * DD + d0) * NTOT + n0;
    __shared__ __align__(16) float Bsh[64][68];
    __shared__ __align__(16) float Cs[64][68];
    int tid = threadIdx.x, tx = tid & 15, ty = tid >> 4;
#pragma unroll
    for (int k = 0; k < 16; ++k) {
        int idx = tid + k * 256;
        int row = idx >> 6, col = idx & 63;
        Bsh[row][col] = bp[idx];
        Cs[row][col] = cp[(size_t)row * RR + col];
    }
    __syncthreads();
    float acc[4][4] = {};
#pragma unroll
    for (int q = 0; q < 16; ++q) {
        float4 bv[4], cv[4];
#pragma unroll
        for (int i = 0; i < 4; ++i) bv[i] = *(const float4*)&Bsh[ty + 16 * i][4 * q];
#pragma unroll
        for (int j = 0; j < 4; ++j) cv[j] = *(const float4*)&Cs[tx + 16 * j][4 * q];
#pragma unroll
        for (int i = 0; i < 4; ++i)
#pragma unroll
            for (int j = 0; j < 4; ++j)
                acc[i][j] += bv[i].x * cv[j].x + bv[i].y * cv[j].y +
                             bv[i].z * cv[j].z + bv[i].w * cv[j].w;
    }
#pragma unroll
    for (int i = 0; i < 4; ++i)
#pragma unroll
        for (int j = 0; j < 4; ++j)
            op[(size_t)(ty + 16 * i) * NTOT + tx + 16 * j] = acc[i][j];
}

// ---------------------------------------------------------------------------
extern "C" void kernel_launch(void* const* d_in, const int* in_sizes, int n_in,
                              void* d_out, int out_size, void* d_ws, size_t ws_size,
                              hipStream_t stream) {
    const float* x = (const float*)d_in[0];      // (2,512,65536)
    const float* bases = (const float*)d_in[1];  // (2,512,64)
    float* out = (float*)d_out;
    float* ws = (float*)d_ws;

    // ws layout (floats): c | b0 | b1 | BtB | CtC | numB | den
    float* c = ws;
    float* b0 = c + (size_t)NB * NTOT * RR;
    float* b1 = b0 + (size_t)NB * DD * RR;
    float* btb = b1 + (size_t)NB * DD * RR;
    float* ctc = btb + (size_t)NB * RR * RR;
    float* nB = ctc + (size_t)NB * RR * RR;
    float* den = nB + (size_t)NB * DD * RR;
    size_t need = ((size_t)(den - ws) + (size_t)NB * NTOT * RR) * sizeof(float);
    if (ws_size < need) den = out;  // out is fully overwritten by xhat at the end

    colnorm_kernel<<<NB * RR, 64, 0, stream>>>(bases, b0);
    hipMemsetAsync(btb, 0, (size_t)NB * RR * RR * sizeof(float), stream);
    ata2_kernel<<<dim3(16, NB), 256, 0, stream>>>(b0, btb, 32, (long)DD * RR);

    // coef = softmax(x^T b)  (raw x)
    xtb2_kernel<0><<<dim3(NTOT / 256, NB), 256, 0, stream>>>(x, b0, nullptr, c, 0, 0);

    float* bcur = b0;
    float* bnxt = b1;
    for (int step = 0; step < 6; ++step) {
        cden_kernel<<<dim3(NTOT / 64, NB), 256, 0, stream>>>(c, btb, den, step > 0 ? 1 : 0);
        xtb2_kernel<1><<<dim3(NTOT / 256, NB), 256, 0, stream>>>(
            x, bcur, den, c, 1, step > 0 ? 1 : 0);
        hipMemsetAsync(ctc, 0, (size_t)NB * RR * RR * sizeof(float), stream);
        hipMemsetAsync(nB, 0, (size_t)NB * DD * RR * sizeof(float), stream);
        ata2_kernel<<<dim3(128, NB), 256, 0, stream>>>(c, ctc, 512, (long)NTOT * RR);
        xtc2_kernel<<<dim3(32, 8, NB), 256, 0, stream>>>(x, c, nB);
        updb_kernel<<<dim3(8, NB), 256, 0, stream>>>(bcur, nB, ctc, bnxt);
        colnorm_kernel<<<NB * RR, 64, 0, stream>>>(bnxt, bnxt);
        float* t = bcur; bcur = bnxt; bnxt = t;
        hipMemsetAsync(btb, 0, (size_t)NB * RR * RR * sizeof(float), stream);
        ata2_kernel<<<dim3(16, NB), 256, 0, stream>>>(bcur, btb, 32, (long)DD * RR);
    }

    // compute_coef
    cden_kernel<<<dim3(NTOT / 64, NB), 256, 0, stream>>>(c, btb, den, 1);
    xtb2_kernel<1><<<dim3(NTOT / 256, NB), 256, 0, stream>>>(x, bcur, den, c, 1, 1);

    // x_hat = b @ c_new^T
    xhat_kernel<<<dim3(NTOT / 64, DD / 64, NB), 256, 0, stream>>>(bcur, c, out);
}

// Round 3
// 1942.002 us; speedup vs baseline: 2.6231x; 1.4880x over previous
//
#include <hip/hip_runtime.h>
#include <math.h>

#define DD   512
#define NTOT 65536
#define RR   64
#define NB   2
#define EPSV 1e-6f

typedef unsigned short u16;
typedef __attribute__((ext_vector_type(8))) short bf16x8;
typedef __attribute__((ext_vector_type(8))) unsigned short us8;
typedef __attribute__((ext_vector_type(4))) float f32x4;

__device__ inline u16 f2bf(float f) {
    union { float f; unsigned u; } x; x.f = f;
    unsigned r = x.u + 0x7FFFu + ((x.u >> 16) & 1u);   // RNE (no NaN here)
    return (u16)(r >> 16);
}
__device__ inline float bf2f(u16 h) {
    union { unsigned u; float f; } x; x.u = ((unsigned)h) << 16;
    return x.f;
}

#define MFMA16(a, b, c) __builtin_amdgcn_mfma_f32_16x16x32_bf16((a), (b), (c), 0, 0, 0)

// ---------------------------------------------------------------------------
// convert_x: x fp32 [s][d][n] -> xd bf16 clamped [s][d][n] + xT bf16 clamped
// [s][n][d]. Both live in d_out (128 MiB each, exactly filling it).
// grid (NTOT/64, DD/64, NB).
// ---------------------------------------------------------------------------
__global__ __launch_bounds__(256) void convert_x_kernel(const float* __restrict__ x,
                                                        u16* __restrict__ xd,
                                                        u16* __restrict__ xT) {
    int s = blockIdx.z, d0 = blockIdx.y * 64, n0 = blockIdx.x * 64;
    const float* xp = x + ((size_t)s * DD + d0) * NTOT + n0;
    u16* xdp = xd + ((size_t)s * DD + d0) * NTOT + n0;
    u16* xtp = xT + ((size_t)s * NTOT + n0) * DD + d0;
    __shared__ u16 L[64][66];
    int tid = threadIdx.x;
#pragma unroll
    for (int k = 0; k < 4; ++k) {
        int f4 = tid + k * 256;
        int dr = f4 >> 4, c4 = (f4 & 15) * 4;
        float4 v = *(const float4*)&xp[(size_t)dr * NTOT + c4];
        u16 h0 = f2bf(fmaxf(v.x, EPSV));
        u16 h1 = f2bf(fmaxf(v.y, EPSV));
        u16 h2 = f2bf(fmaxf(v.z, EPSV));
        u16 h3 = f2bf(fmaxf(v.w, EPSV));
        xdp[(size_t)dr * NTOT + c4 + 0] = h0;
        xdp[(size_t)dr * NTOT + c4 + 1] = h1;
        xdp[(size_t)dr * NTOT + c4 + 2] = h2;
        xdp[(size_t)dr * NTOT + c4 + 3] = h3;
        L[dr][c4 + 0] = h0; L[dr][c4 + 1] = h1;
        L[dr][c4 + 2] = h2; L[dr][c4 + 3] = h3;
    }
    __syncthreads();
#pragma unroll
    for (int k = 0; k < 2; ++k) {
        int f8 = tid + k * 256;
        int nr = f8 >> 3, d8 = (f8 & 7) * 8;
        us8 w;
#pragma unroll
        for (int i = 0; i < 8; ++i) w[i] = L[d8 + i][nr];
        *(us8*)&xtp[(size_t)nr * DD + d8] = w;
    }
}

// ---------------------------------------------------------------------------
// colnorm: dst[:,r] = src[:,r] / max(||src[:,r]||, 1e-12) per (batch, r).
// ---------------------------------------------------------------------------
__global__ __launch_bounds__(64) void colnorm_kernel(const float* __restrict__ src,
                                                     float* __restrict__ dst) {
    int col = blockIdx.x;
    int s = col >> 6, r = col & 63;
    const float* p = src + (size_t)s * DD * RR + r;
    float* q = dst + (size_t)s * DD * RR + r;
    int lane = threadIdx.x;
    float v[8];
    float ss = 0.f;
#pragma unroll
    for (int k = 0; k < 8; ++k) {
        v[k] = p[(size_t)(lane + 64 * k) * RR];
        ss += v[k] * v[k];
    }
#pragma unroll
    for (int m = 1; m < 64; m <<= 1) ss += __shfl_xor(ss, m);
    float inv = 1.f / fmaxf(sqrtf(ss), 1e-12f);
#pragma unroll
    for (int k = 0; k < 8; ++k)
        q[(size_t)(lane + 64 * k) * RR] = v[k] * inv;
}

// ---------------------------------------------------------------------------
// ata2 (fp32): BtB[k][j] += sum_d b[d][k]*b[d][j].  grid (16, NB), rpb=32.
// ---------------------------------------------------------------------------
__global__ __launch_bounds__(256) void ata2_kernel(const float* __restrict__ A,
                                                   float* __restrict__ outp,
                                                   int rpb, long bstride) {
    int s = blockIdx.y;
    long r0 = (long)blockIdx.x * rpb;
    const float* Ap = A + (size_t)s * bstride;
    float* op = outp + (size_t)s * RR * RR;
    __shared__ __align__(16) float As[32][68];
    int tid = threadIdx.x, tx = tid & 15, ty = tid >> 4;
    float4 g[2];
#pragma unroll
    for (int w = 0; w < 2; ++w) {
        int f4 = w * 256 + tid, row = f4 >> 4, c4 = f4 & 15;
        g[w] = *(const float4*)&Ap[(size_t)(r0 + row) * RR + 4 * c4];
    }
    float acc[4][4] = {};
    int nst = rpb / 32;
    for (int st = 0; st < nst; ++st) {
        __syncthreads();
#pragma unroll
        for (int w = 0; w < 2; ++w) {
            int f4 = w * 256 + tid, row = f4 >> 4, c4 = f4 & 15;
            *(float4*)&As[row][4 * c4] = g[w];
        }
        if (st + 1 < nst) {
            long rb = r0 + (long)(st + 1) * 32;
#pragma unroll
            for (int w = 0; w < 2; ++w) {
                int f4 = w * 256 + tid, row = f4 >> 4, c4 = f4 & 15;
                g[w] = *(const float4*)&Ap[(size_t)(rb + row) * RR + 4 * c4];
            }
        }
        __syncthreads();
#pragma unroll
        for (int k = 0; k < 32; ++k) {
            float4 av = *(const float4*)&As[k][4 * ty];
            float4 bv = *(const float4*)&As[k][4 * tx];
            float ar[4] = {av.x, av.y, av.z, av.w};
            float br[4] = {bv.x, bv.y, bv.z, bv.w};
#pragma unroll
            for (int i = 0; i < 4; ++i)
#pragma unroll
                for (int j = 0; j < 4; ++j) acc[i][j] += ar[i] * br[j];
        }
    }
#pragma unroll
    for (int i = 0; i < 4; ++i)
#pragma unroll
        for (int j = 0; j < 4; ++j)
            atomicAdd(&op[(4 * ty + i) * RR + 4 * tx + j], acc[i][j]);
}

// ---------------------------------------------------------------------------
// bcast: b fp32 [d][r] -> b_bf [d][r], bT_bf [r][d]; btb fp32 -> btb_bf.
// grid (NB), 256 thr.
// ---------------------------------------------------------------------------
__global__ __launch_bounds__(256) void bcast_kernel(const float* __restrict__ b,
                                                    const float* __restrict__ btb,
                                                    u16* __restrict__ b_bf,
                                                    u16* __restrict__ bT_bf,
                                                    u16* __restrict__ btb_bf) {
    int s = blockIdx.x, tid = threadIdx.x;
    const float* bp = b + (size_t)s * DD * RR;
    u16* bb = b_bf + (size_t)s * DD * RR;
    u16* bt = bT_bf + (size_t)s * RR * DD;
    for (int i = tid; i < DD * RR; i += 256) {
        int d = i >> 6, r = i & 63;
        u16 h = f2bf(bp[i]);
        bb[i] = h;
        bt[r * DD + d] = h;
    }
    const float* tp = btb + (size_t)s * RR * RR;
    u16* tb = btb_bf + (size_t)s * RR * RR;
    for (int i = tid; i < RR * RR; i += 256) tb[i] = f2bf(tp[i]);
}

// ---------------------------------------------------------------------------
// init: coef = softmax_r(x^T b) on RAW fp32 x; writes cTf_bf [r][n] bf16.
// (round-2 fp32 xtb2 MODE 0 with transposed bf16 epilogue)
// grid (NTOT/256, NB).
// ---------------------------------------------------------------------------
__global__ __launch_bounds__(256, 2) void init_coef_kernel(const float* __restrict__ x,
                                                           const float* __restrict__ bmat,
                                                           u16* __restrict__ cT) {
    int s = blockIdx.y;
    int n0 = blockIdx.x * 256;
    const float* xp = x + (size_t)s * DD * NTOT + n0;
    const float* bp = bmat + (size_t)s * DD * RR;
    u16* cTp = cT + (size_t)s * RR * NTOT;
    __shared__ __align__(16) float Xs[16][256];
    __shared__ __align__(16) float Bs[16][64];
    int tid = threadIdx.x, tx = tid & 7, ty = tid >> 3;

    float4 gx[4];
    float4 gb;
#pragma unroll
    for (int w = 0; w < 4; ++w) {
        int idx = w * 256 + tid, row = idx >> 6, c4 = idx & 63;
        gx[w] = *(const float4*)&xp[(size_t)row * NTOT + 4 * c4];
    }
    {
        int row = tid >> 4, c4 = tid & 15;
        gb = *(const float4*)&bp[(size_t)row * RR + 4 * c4];
    }
    float acc[8][8] = {};
    for (int st = 0; st < 32; ++st) {
        __syncthreads();
#pragma unroll
        for (int w = 0; w < 4; ++w) {
            int idx = w * 256 + tid, row = idx >> 6, c4 = idx & 63;
            *(float4*)&Xs[row][4 * c4] = gx[w];
        }
        {
            int row = tid >> 4, c4 = tid & 15;
            *(float4*)&Bs[row][4 * c4] = gb;
        }
        if (st + 1 < 32) {
            int d0 = (st + 1) * 16;
#pragma unroll
            for (int w = 0; w < 4; ++w) {
                int idx = w * 256 + tid, row = idx >> 6, c4 = idx & 63;
                gx[w] = *(const float4*)&xp[(size_t)(d0 + row) * NTOT + 4 * c4];
            }
            int row = tid >> 4, c4 = tid & 15;
            gb = *(const float4*)&bp[(size_t)(d0 + row) * RR + 4 * c4];
        }
        __syncthreads();
#pragma unroll
        for (int k = 0; k < 16; ++k) {
            float4 x0 = *(const float4*)&Xs[k][8 * ty];
            float4 x1 = *(const float4*)&Xs[k][8 * ty + 4];
            float4 b0 = *(const float4*)&Bs[k][8 * tx];
            float4 b1 = *(const float4*)&Bs[k][8 * tx + 4];
            float xr[8] = {x0.x, x0.y, x0.z, x0.w, x1.x, x1.y, x1.z, x1.w};
            float br[8] = {b0.x, b0.y, b0.z, b0.w, b1.x, b1.y, b1.z, b1.w};
#pragma unroll
            for (int i = 0; i < 8; ++i)
#pragma unroll
                for (int j = 0; j < 8; ++j) acc[i][j] += xr[i] * br[j];
        }
    }
#pragma unroll
    for (int i = 0; i < 8; ++i) {
        float m = acc[i][0];
#pragma unroll
        for (int j = 1; j < 8; ++j) m = fmaxf(m, acc[i][j]);
        m = fmaxf(m, __shfl_xor(m, 1));
        m = fmaxf(m, __shfl_xor(m, 2));
        m = fmaxf(m, __shfl_xor(m, 4));
        float e[8];
        float ssum = 0.f;
#pragma unroll
        for (int j = 0; j < 8; ++j) {
            e[j] = expf(acc[i][j] - m);
            ssum += e[j];
        }
        ssum += __shfl_xor(ssum, 1);
        ssum += __shfl_xor(ssum, 2);
        ssum += __shfl_xor(ssum, 4);
        float inv = 1.f / ssum;
        int n = n0 + 8 * ty + i;
#pragma unroll
        for (int j = 0; j < 8; ++j)
            cTp[(size_t)(8 * tx + j) * NTOT + n] = f2bf(e[j] * inv);
    }
}

// ---------------------------------------------------------------------------
// transp_c: cTf_bf [r][n] -> c_nb [n][r] bf16, optional integer-domain clamp
// (c >= 0 always, so unsigned max against bits(bf16(1e-6)) = 0x3586).
// grid (NTOT/64, NB).
// ---------------------------------------------------------------------------
__global__ __launch_bounds__(256) void transp_c_kernel(const u16* __restrict__ cT,
                                                       u16* __restrict__ cnb,
                                                       int clampf) {
    int s = blockIdx.y;
    int n0 = blockIdx.x * 64;
    const u16* cp = cT + (size_t)s * RR * NTOT + n0;
    u16* op = cnb + ((size_t)s * NTOT + n0) * RR;
    __shared__ u16 L[64][66];
    int tid = threadIdx.x;
#pragma unroll
    for (int k = 0; k < 2; ++k) {
        int f8 = tid + k * 256;
        int r = f8 >> 3, c8 = (f8 & 7) * 8;
        us8 v = *(const us8*)&cp[(size_t)r * NTOT + c8];
        if (clampf) {
#pragma unroll
            for (int i = 0; i < 8; ++i) v[i] = v[i] < 0x3586u ? (u16)0x3586u : v[i];
        }
#pragma unroll
        for (int i = 0; i < 8; ++i) L[r][c8 + i] = v[i];
    }
    __syncthreads();
#pragma unroll
    for (int k = 0; k < 2; ++k) {
        int f8 = tid + k * 256;
        int nr = f8 >> 3, r8 = (f8 & 7) * 8;
        us8 w;
#pragma unroll
        for (int i = 0; i < 8; ++i) w[i] = L[r8 + i][nr];
        *(us8*)&op[(size_t)nr * RR + r8] = w;
    }
}

// ---------------------------------------------------------------------------
// xtb_mfma: fused denC + numC + c-update (MU c-step / compute_coef).
//  phase1: denT[r][n] = BtB_bf @ c_nb           (K=64)
//  phase2: T^T[r][n]  = bT_bf @ xT_clamped      (K=512)
//  epilogue: c = clamp?(c) * T / (den + EPS), written back to cTf_bf.
// Wave: 32 n x 64 r. grid (NTOT/128, NB), 256 thr, no LDS.
// ---------------------------------------------------------------------------
__global__ __launch_bounds__(256) void xtb_mfma_kernel(const u16* __restrict__ xT,
                                                       const u16* __restrict__ bT,
                                                       const u16* __restrict__ btbbf,
                                                       const u16* __restrict__ cnb,
                                                       u16* __restrict__ cT,
                                                       int clampc) {
    int s = blockIdx.y;
    int n0 = blockIdx.x * 128;
    int tid = threadIdx.x;
    int w = tid >> 6, lane = tid & 63, g = lane >> 4, l15 = lane & 15;
    int nw = n0 + w * 32;
    const u16* xTp = xT + (size_t)s * NTOT * DD;
    const u16* bTp = bT + (size_t)s * RR * DD;
    const u16* bb = btbbf + (size_t)s * RR * RR;
    const u16* cnp = cnb + (size_t)s * NTOT * RR;
    u16* cTp = cT + (size_t)s * RR * NTOT;

    f32x4 zero = {0.f, 0.f, 0.f, 0.f};
    f32x4 accD[4][2], accT[4][2];
#pragma unroll
    for (int rs = 0; rs < 4; ++rs)
#pragma unroll
        for (int ns = 0; ns < 2; ++ns) { accD[rs][ns] = zero; accT[rs][ns] = zero; }

    // phase 1: den
#pragma unroll
    for (int k0 = 0; k0 < 64; k0 += 32) {
        bf16x8 a[4], b[2];
#pragma unroll
        for (int rs = 0; rs < 4; ++rs)
            a[rs] = *(const bf16x8*)&bb[(rs * 16 + l15) * RR + k0 + g * 8];
#pragma unroll
        for (int ns = 0; ns < 2; ++ns)
            b[ns] = *(const bf16x8*)&cnp[(size_t)(nw + ns * 16 + l15) * RR + k0 + g * 8];
#pragma unroll
        for (int rs = 0; rs < 4; ++rs)
#pragma unroll
            for (int ns = 0; ns < 2; ++ns)
                accD[rs][ns] = MFMA16(a[rs], b[ns], accD[rs][ns]);
    }
    // phase 2: T
    for (int k0 = 0; k0 < DD; k0 += 32) {
        bf16x8 a[4], b[2];
#pragma unroll
        for (int rs = 0; rs < 4; ++rs)
            a[rs] = *(const bf16x8*)&bTp[(rs * 16 + l15) * DD + k0 + g * 8];
#pragma unroll
        for (int ns = 0; ns < 2; ++ns)
            b[ns] = *(const bf16x8*)&xTp[(size_t)(nw + ns * 16 + l15) * DD + k0 + g * 8];
#pragma unroll
        for (int rs = 0; rs < 4; ++rs)
#pragma unroll
            for (int ns = 0; ns < 2; ++ns)
                accT[rs][ns] = MFMA16(a[rs], b[ns], accT[rs][ns]);
    }
    // epilogue
#pragma unroll
    for (int rs = 0; rs < 4; ++rs)
#pragma unroll
        for (int ns = 0; ns < 2; ++ns)
#pragma unroll
            for (int e = 0; e < 4; ++e) {
                int r = rs * 16 + g * 4 + e;
                int n = nw + ns * 16 + l15;
                size_t off = (size_t)r * NTOT + n;
                float cin = bf2f(cTp[off]);
                if (clampc) cin = fmaxf(cin, EPSV);
                float v = cin * accT[rs][ns][e] / (accD[rs][ns][e] + EPSV);
                cTp[off] = f2bf(v);
            }
}

// ---------------------------------------------------------------------------
// ctc_mfma: CtC[i][j] += sum_n c[n][i]*c[n][j] from cTf_bf. K-split atomic.
// grid (64, NB): chunk 1024. Wave w: rows 16w..16w+15, all 64 cols.
// ---------------------------------------------------------------------------
__global__ __launch_bounds__(256) void ctc_mfma_kernel(const u16* __restrict__ cT,
                                                       float* __restrict__ ctc) {
    int s = blockIdx.y;
    int kbase = blockIdx.x * 1024;
    int tid = threadIdx.x;
    int w = tid >> 6, lane = tid & 63, g = lane >> 4, l15 = lane & 15;
    const u16* cTp = cT + (size_t)s * RR * NTOT;
    f32x4 zero = {0.f, 0.f, 0.f, 0.f};
    f32x4 acc[4];
#pragma unroll
    for (int cs = 0; cs < 4; ++cs) acc[cs] = zero;
    for (int k0 = kbase; k0 < kbase + 1024; k0 += 32) {
        bf16x8 a = *(const bf16x8*)&cTp[(size_t)(w * 16 + l15) * NTOT + k0 + g * 8];
        bf16x8 b[4];
#pragma unroll
        for (int cs = 0; cs < 4; ++cs)
            b[cs] = *(const bf16x8*)&cTp[(size_t)(cs * 16 + l15) * NTOT + k0 + g * 8];
#pragma unroll
        for (int cs = 0; cs < 4; ++cs) acc[cs] = MFMA16(a, b[cs], acc[cs]);
    }
    float* op = ctc + (size_t)s * RR * RR;
#pragma unroll
    for (int cs = 0; cs < 4; ++cs)
#pragma unroll
        for (int e = 0; e < 4; ++e)
            atomicAdd(&op[(w * 16 + g * 4 + e) * RR + cs * 16 + l15], acc[cs][e]);
}

// ---------------------------------------------------------------------------
// xtc_mfma: numB[d][r] += sum_n xc[d][n]*c[n][r]. A = xd_clamped bf16,
// B = cTf_bf (fresh unclamped c). grid (32 ksplit, 8 dtile, NB); chunk 2048.
// Wave w: d-rows dtile+16w.., all 64 r.
// ---------------------------------------------------------------------------
__global__ __launch_bounds__(256) void xtc_mfma_kernel(const u16* __restrict__ xd,
                                                       const u16* __restrict__ cT,
                                                       float* __restrict__ numB) {
    int s = blockIdx.z;
    int dtile = blockIdx.y * 64;
    int kbase = blockIdx.x * 2048;
    int tid = threadIdx.x;
    int w = tid >> 6, lane = tid & 63, g = lane >> 4, l15 = lane & 15;
    const u16* xdp = xd + (size_t)s * DD * NTOT;
    const u16* cTp = cT + (size_t)s * RR * NTOT;
    int drow = dtile + w * 16 + l15;
    f32x4 zero = {0.f, 0.f, 0.f, 0.f};
    f32x4 acc[4];
#pragma unroll
    for (int rs = 0; rs < 4; ++rs) acc[rs] = zero;
    for (int k0 = kbase; k0 < kbase + 2048; k0 += 32) {
        bf16x8 a = *(const bf16x8*)&xdp[(size_t)drow * NTOT + k0 + g * 8];
        bf16x8 b[4];
#pragma unroll
        for (int rs = 0; rs < 4; ++rs)
            b[rs] = *(const bf16x8*)&cTp[(size_t)(rs * 16 + l15) * NTOT + k0 + g * 8];
#pragma unroll
        for (int rs = 0; rs < 4; ++rs) acc[rs] = MFMA16(a, b[rs], acc[rs]);
    }
    float* op = numB + (size_t)s * DD * RR;
#pragma unroll
    for (int rs = 0; rs < 4; ++rs)
#pragma unroll
        for (int e = 0; e < 4; ++e)
            atomicAdd(&op[(dtile + w * 16 + g * 4 + e) * RR + rs * 16 + l15], acc[rs][e]);
}

// ---------------------------------------------------------------------------
// updb (fp32, in-place safe): b = max(b*numB/(b@CtC+EPS), EPS). grid (8, NB).
// ---------------------------------------------------------------------------
__global__ __launch_bounds__(256) void updb_kernel(const float* __restrict__ bin,
                                                   const float* __restrict__ numB,
                                                   const float* __restrict__ ctcG,
                                                   float* __restrict__ bout) {
    int s = blockIdx.y;
    int d0 = blockIdx.x * 64;
    const float* bp = bin + ((size_t)s * DD + d0) * RR;
    const float* np_ = numB + ((size_t)s * DD + d0) * RR;
    float* op = bout + ((size_t)s * DD + d0) * RR;
    const float* cc = ctcG + (size_t)s * RR * RR;
    __shared__ __align__(16) float Bsh[64][68];
    __shared__ __align__(16) float Ct[64][68];
    int tid = threadIdx.x, tx = tid & 15, ty = tid >> 4;
#pragma unroll
    for (int k = 0; k < 16; ++k) {
        int idx = tid + k * 256;
        int r_ = idx >> 6, col = idx & 63;
        Bsh[r_][col] = bp[idx];
        Ct[r_][col] = cc[idx];
    }
    __syncthreads();
#pragma unroll
    for (int i = 0; i < 4; ++i) {
        int d = 4 * ty + i;
        float den[4] = {};
#pragma unroll
        for (int k = 0; k < 64; ++k) {
            float bv = Bsh[d][k];
            float4 ct = *(const float4*)&Ct[k][4 * tx];
            den[0] += bv * ct.x;
            den[1] += bv * ct.y;
            den[2] += bv * ct.z;
            den[3] += bv * ct.w;
        }
        float4 b4 = *(const float4*)&Bsh[d][4 * tx];
        float4 n4 = *(const float4*)&np_[(size_t)d * RR + 4 * tx];
        float4 o;
        o.x = fmaxf(b4.x * n4.x / (den[0] + EPSV), EPSV);
        o.y = fmaxf(b4.y * n4.y / (den[1] + EPSV), EPSV);
        o.z = fmaxf(b4.z * n4.z / (den[2] + EPSV), EPSV);
        o.w = fmaxf(b4.w * n4.w / (den[3] + EPSV), EPSV);
        *(float4*)&op[(size_t)d * RR + 4 * tx] = o;
    }
}

// ---------------------------------------------------------------------------
// xhat_mfma: out[d][n] = sum_r b[d][r]*c_new[n][r]. A=b_bf, B=c_nb. K=64.
// grid (NTOT/64, DD/64, NB). Wave w: d-rows d0+16w.., 64 n.
// ---------------------------------------------------------------------------
__global__ __launch_bounds__(256) void xhat_mfma_kernel(const u16* __restrict__ b_bf,
                                                        const u16* __restrict__ cnb,
                                                        float* __restrict__ outp) {
    int s = blockIdx.z;
    int d0 = blockIdx.y * 64;
    int n0 = blockIdx.x * 64;
    int tid = threadIdx.x;
    int w = tid >> 6, lane = tid & 63, g = lane >> 4, l15 = lane & 15;
    const u16* bp = b_bf + (size_t)s * DD * RR;
    const u16* cp = cnb + (size_t)s * NTOT * RR;
    f32x4 zero = {0.f, 0.f, 0.f, 0.f};
    f32x4 acc[4];
#pragma unroll
    for (int ns = 0; ns < 4; ++ns) acc[ns] = zero;
#pragma unroll
    for (int k0 = 0; k0 < 64; k0 += 32) {
        bf16x8 a = *(const bf16x8*)&bp[(d0 + w * 16 + l15) * RR + k0 + g * 8];
        bf16x8 b[4];
#pragma unroll
        for (int ns = 0; ns < 4; ++ns)
            b[ns] = *(const bf16x8*)&cp[(size_t)(n0 + ns * 16 + l15) * RR + k0 + g * 8];
#pragma unroll
        for (int ns = 0; ns < 4; ++ns) acc[ns] = MFMA16(a, b[ns], acc[ns]);
    }
    float* op = outp + (size_t)s * DD * NTOT;
#pragma unroll
    for (int ns = 0; ns < 4; ++ns)
#pragma unroll
        for (int e = 0; e < 4; ++e)
            op[(size_t)(d0 + w * 16 + g * 4 + e) * NTOT + n0 + ns * 16 + l15] = acc[ns][e];
}

// ---------------------------------------------------------------------------
extern "C" void kernel_launch(void* const* d_in, const int* in_sizes, int n_in,
                              void* d_out, int out_size, void* d_ws, size_t ws_size,
                              hipStream_t stream) {
    const float* x = (const float*)d_in[0];      // (2,512,65536) fp32
    const float* bases = (const float*)d_in[1];  // (2,512,64)
    float* out = (float*)d_out;
    char* ws = (char*)d_ws;

    // --- out doubles as bf16 x storage until xhat overwrites it ---
    u16* xT = (u16*)d_out;                             // [NB][NTOT][DD] clamped
    u16* xd = (u16*)d_out + (size_t)NB * NTOT * DD;    // [NB][DD][NTOT] clamped

    // --- ws layout (34,406,400 B total, fits proven round-1/2 footprint) ---
    u16* cTf = (u16*)ws;                                        // 16,777,216 B
    u16* cnb = (u16*)(ws + 16777216);                           // 16,777,216 B
    float* b0 = (float*)(ws + 33554432);                        //    262,144 B
    float* btb = (float*)(ws + 33816576);                       //     32,768 B
    float* ctc = (float*)(ws + 33849344);                       //     32,768 B
    float* nB = (float*)(ws + 33882112);                        //    262,144 B
    u16* btb_bf = (u16*)(ws + 33882112);                        // alias numB[0:16K]
    u16* bT_bf = (u16*)(ws + 34144256);                         //    131,072 B
    u16* b_bf = (u16*)(ws + 34275328);                          //    131,072 B

    // 1) bf16 copies of x (clamped) into out
    convert_x_kernel<<<dim3(NTOT / 64, DD / 64, NB), 256, 0, stream>>>(x, xd, xT);

    // 2) b = l2norm(bases); BtB; bf16 casts
    colnorm_kernel<<<NB * RR, 64, 0, stream>>>(bases, b0);
    hipMemsetAsync(btb, 0, (size_t)NB * RR * RR * sizeof(float), stream);
    ata2_kernel<<<dim3(16, NB), 256, 0, stream>>>(b0, btb, 32, (long)DD * RR);
    bcast_kernel<<<NB, 256, 0, stream>>>(b0, btb, b_bf, bT_bf, btb_bf);

    // 3) coef = softmax(x^T b) on raw fp32 x -> cTf_bf
    init_coef_kernel<<<dim3(NTOT / 256, NB), 256, 0, stream>>>(x, b0, cTf);

    // 4) 6 MU steps
    for (int step = 0; step < 6; ++step) {
        transp_c_kernel<<<dim3(NTOT / 64, NB), 256, 0, stream>>>(cTf, cnb, step > 0 ? 1 : 0);
        xtb_mfma_kernel<<<dim3(NTOT / 128, NB), 256, 0, stream>>>(
            xT, bT_bf, btb_bf, cnb, cTf, step > 0 ? 1 : 0);
        hipMemsetAsync(ctc, 0, 32768 + 262144, stream);  // ctc + numB contiguous
        ctc_mfma_kernel<<<dim3(64, NB), 256, 0, stream>>>(cTf, ctc);
        xtc_mfma_kernel<<<dim3(32, 8, NB), 256, 0, stream>>>(xd, cTf, nB);
        updb_kernel<<<dim3(8, NB), 256, 0, stream>>>(b0, nB, ctc, b0);  // in-place safe
        colnorm_kernel<<<NB * RR, 64, 0, stream>>>(b0, b0);
        hipMemsetAsync(btb, 0, (size_t)NB * RR * RR * sizeof(float), stream);
        ata2_kernel<<<dim3(16, NB), 256, 0, stream>>>(b0, btb, 32, (long)DD * RR);
        bcast_kernel<<<NB, 256, 0, stream>>>(b0, btb, b_bf, bT_bf, btb_bf);
    }

    // 5) compute_coef: c_new = clamp(coef)*numC/(clamp(coef)@BtB+EPS)
    transp_c_kernel<<<dim3(NTOT / 64, NB), 256, 0, stream>>>(cTf, cnb, 1);
    xtb_mfma_kernel<<<dim3(NTOT / 128, NB), 256, 0, stream>>>(
        xT, bT_bf, btb_bf, cnb, cTf, 1);

    // 6) x_hat = b @ c_new^T  (c_new unclamped -> c_nb, then MFMA into out)
    transp_c_kernel<<<dim3(NTOT / 64, NB), 256, 0, stream>>>(cTf, cnb, 0);
    xhat_mfma_kernel<<<dim3(NTOT / 64, DD / 64, NB), 256, 0, stream>>>(b_bf, cnb, out);
}